// Round 3
// baseline (217.465 us; speedup 1.0000x reference)
//
#include <hip/hip_runtime.h>

// Problem constants: B=32, T=512, F=513, S=3
#define BB 32
#define NN (512 * 513)                    // 262656 elements per (b, source)
#define FLOATS_PER_B (NN * 3)             // 787968 floats per batch slice
#define CHUNKS_PER_B (FLOATS_PER_B / 12)  // 65664 chunks of 12 floats
#define THREADS 256
#define BLOCKS_PER_B 64
#define CHUNK_STRIDE (BLOCKS_PER_B * THREADS)  // 16384 chunks per sweep (~4 iters/thread)

// --- Kernel 1: per-block partial sums of |est[b,n,i] - tgt[b,n,j]| ---
// No LDS staging, no atomics. Register double-buffer keeps 6 float4 loads in
// flight during each chunk's compute to maximize memory-level parallelism.
__global__ __launch_bounds__(THREADS) void pil_partial(
        const float* __restrict__ est,
        const float* __restrict__ tgt,
        float* __restrict__ ws) {
    const int b   = blockIdx.x / BLOCKS_PER_B;
    const int blk = blockIdx.x % BLOCKS_PER_B;
    const int tid = threadIdx.x;

    const float4* eb = (const float4*)(est + (size_t)b * FLOATS_PER_B);
    const float4* tb = (const float4*)(tgt + (size_t)b * FLOATS_PER_B);

    float acc[9];
#pragma unroll
    for (int k = 0; k < 9; ++k) acc[k] = 0.0f;

    int c = blk * THREADS + tid;
    bool valid = (c < CHUNKS_PER_B);

    // Prologue: load current chunk (12 floats from each array).
    float4 ce0, ce1, ce2, ct0, ct1, ct2;
    if (valid) {
        ce0 = eb[3 * c + 0]; ce1 = eb[3 * c + 1]; ce2 = eb[3 * c + 2];
        ct0 = tb[3 * c + 0]; ct1 = tb[3 * c + 1]; ct2 = tb[3 * c + 2];
    }

    while (valid) {
        // Prefetch next chunk BEFORE computing current: these 6 loads stay in
        // flight across the 72-op compute below.
        const int cn = c + CHUNK_STRIDE;
        const bool nvalid = (cn < CHUNKS_PER_B);
        float4 ne0, ne1, ne2, nt0, nt1, nt2;
        if (nvalid) {
            ne0 = eb[3 * cn + 0]; ne1 = eb[3 * cn + 1]; ne2 = eb[3 * cn + 2];
            nt0 = tb[3 * cn + 0]; nt1 = tb[3 * cn + 1]; nt2 = tb[3 * cn + 2];
        }

        const float e[12] = {ce0.x, ce0.y, ce0.z, ce0.w, ce1.x, ce1.y,
                             ce1.z, ce1.w, ce2.x, ce2.y, ce2.z, ce2.w};
        const float t[12] = {ct0.x, ct0.y, ct0.z, ct0.w, ct1.x, ct1.y,
                             ct1.z, ct1.w, ct2.x, ct2.y, ct2.z, ct2.w};
#pragma unroll
        for (int g = 0; g < 4; ++g) {
#pragma unroll
            for (int i = 0; i < 3; ++i) {
#pragma unroll
                for (int j = 0; j < 3; ++j) {
                    acc[i * 3 + j] += fabsf(e[3 * g + i] - t[3 * g + j]);
                }
            }
        }

        // Rotate buffers (forces the vmcnt wait only here, after compute).
        ce0 = ne0; ce1 = ne1; ce2 = ne2;
        ct0 = nt0; ct1 = nt1; ct2 = nt2;
        c = cn;
        valid = nvalid;
    }

    // Wave-level reduction (64 lanes) of each of the 9 accumulators.
#pragma unroll
    for (int k = 0; k < 9; ++k) {
        float v = acc[k];
#pragma unroll
        for (int off = 32; off > 0; off >>= 1) v += __shfl_down(v, off);
        acc[k] = v;
    }

    __shared__ float sred[THREADS / 64][9];
    const int wave = tid >> 6;
    const int lane = tid & 63;
    if (lane == 0) {
#pragma unroll
        for (int k = 0; k < 9; ++k) sred[wave][k] = acc[k];
    }
    __syncthreads();
    if (tid < 9) {
        float s = 0.0f;
#pragma unroll
        for (int w = 0; w < THREADS / 64; ++w) s += sred[w][tid];
        // Private slot per block: no atomics, no pre-zeroing needed.
        ws[(size_t)(b * BLOCKS_PER_B + blk) * 9 + tid] = s;
    }
}

// --- Kernel 2: sum block partials, per-b perm losses, min, mean over b ---
__global__ void pil_finalize(const float* __restrict__ ws, float* __restrict__ out) {
    __shared__ float sC[BB][9];
    const int p = threadIdx.x;  // 320 threads; first 288 sum partials
    if (p < BB * 9) {
        const int b = p / 9, k = p % 9;
        float s = 0.0f;
        for (int blk = 0; blk < BLOCKS_PER_B; ++blk)
            s += ws[(size_t)(b * BLOCKS_PER_B + blk) * 9 + k];
        sC[b][k] = s;
    }
    __syncthreads();

    if (p < 64) {  // wave 0 only
        float loss = 0.0f;
        if (p < BB) {
            float C[3][3];
#pragma unroll
            for (int i = 0; i < 3; ++i)
#pragma unroll
                for (int j = 0; j < 3; ++j)
                    C[i][j] = sC[p][i * 3 + j] * (1.0f / (float)NN);

            const int P[6][3] = {{0, 1, 2}, {0, 2, 1}, {1, 0, 2},
                                 {1, 2, 0}, {2, 0, 1}, {2, 1, 0}};
            float best = 3.4e38f;
#pragma unroll
            for (int q = 0; q < 6; ++q) {
                float l = (C[P[q][0]][0] + C[P[q][1]][1] + C[P[q][2]][2]) *
                          (1.0f / 3.0f);
                best = fminf(best, l);
            }
            loss = best;
        }
#pragma unroll
        for (int off = 32; off > 0; off >>= 1) loss += __shfl_down(loss, off);
        if (p == 0) out[0] = loss * (1.0f / (float)BB);
    }
}

extern "C" void kernel_launch(void* const* d_in, const int* in_sizes, int n_in,
                              void* d_out, int out_size, void* d_ws, size_t ws_size,
                              hipStream_t stream) {
    const float* est = (const float*)d_in[0];
    const float* tgt = (const float*)d_in[1];
    float* ws  = (float*)d_ws;   // 32*64*9 floats = 73728 B of scratch
    float* out = (float*)d_out;

    pil_partial<<<BB * BLOCKS_PER_B, THREADS, 0, stream>>>(est, tgt, ws);
    pil_finalize<<<1, 320, 0, stream>>>(ws, out);
}